// Round 1
// baseline (544.481 us; speedup 1.0000x reference)
//
#include <hip/hip_runtime.h>
#include <math.h>

// Problem constants
#define BB   64
#define FC   24
#define NN   1000
#define HID  64
#define EMBD 32
#define TT   48
#define FF   8
#define NEMB 1000
#define G3   192
#define INSZ 33

// Decoder tiling
#define CPB  32     // cells per block (M)
#define TPB  256    // 4 waves
#define MT   2      // m-tiles of 16
#define AST  72     // Abuf stride in bf16 elems (16B-aligned rows)
#define XST  32     // Xtile stride in bf16 elems (64B rows, 16B-aligned)

typedef __attribute__((ext_vector_type(8))) short bf16x8;
typedef __attribute__((ext_vector_type(4))) float f32x4;

static __device__ __forceinline__ unsigned short f2bf(float f) {
    unsigned u = __builtin_bit_cast(unsigned, f);
    u += 0x7FFFu + ((u >> 16) & 1u);      // RNE
    return (unsigned short)(u >> 16);
}
// packed RNE f32->bf16: lo = bf16(a), hi = bf16(b)
static __device__ __forceinline__ unsigned cvt_pk_bf16(float a, float b) {
    unsigned r;
    asm("v_cvt_pk_bf16_f32 %0, %1, %2" : "=v"(r) : "v"(a), "v"(b));
    return r;
}
static __device__ __forceinline__ float fast_sigmoid(float v) {
    float e = __builtin_amdgcn_exp2f(-1.4426950408889634f * v);
    return __builtin_amdgcn_rcpf(1.0f + e);
}
static __device__ __forceinline__ float fast_tanh(float v) {
    float vv = fminf(fmaxf(v, -15.0f), 15.0f);
    float e = __builtin_amdgcn_exp2f(2.8853900817779268f * vv);
    return 1.0f - 2.0f * __builtin_amdgcn_rcpf(e + 1.0f);
}

// Single fused kernel: gi's embedding part runs on the matrix pipe
// (chained MFMA with biases folded into the C operand); premul/P3 gone.
__global__ __launch_bounds__(TPB) __attribute__((amdgpu_waves_per_eu(4)))
void gru_decoder(
    const float* __restrict__ X,    // [B][TT][N][F]
    const float* __restrict__ hn0,  // [B*N][HID]
    const float* __restrict__ xn,   // [B][N][1]
    const float* __restrict__ emb,  // [NEMB][EMBD]
    const float* __restrict__ Wih,  // [3*HID][INSZ]
    const float* __restrict__ Whh,  // [3*HID][HID]
    const float* __restrict__ bih,  // [3*HID]
    const float* __restrict__ bhh,  // [3*HID]
    const float* __restrict__ Wout, // [1][HID]
    const float* __restrict__ bout, // [1]
    float* __restrict__ out)        // [B][FC][N][1]
{
    __shared__ __align__(16) unsigned short Abuf[CPB * AST];     // 4608 B
    __shared__ __align__(16) unsigned short Xt[2][CPB * XST];    // 4096 B
    __shared__ int   idxbuf[FC * CPB];                           // 3072 B
    __shared__ float xbuf[CPB];

    const int tid  = threadIdx.x;
    const int lane = tid & 63;
    const int g    = tid >> 6;         // wave 0..3, owns gate-cols g*16..g*16+15
    const int quad = lane >> 4;
    const int l15  = lane & 15;
    const int jcol = g * 16 + l15;
    const int rowb = quad * 4;
    const int cell0 = blockIdx.x * CPB;

    // ---- stage idx for all FC steps ----
    for (int e = tid; e < FC * CPB; e += TPB) {
        int t = e >> 5, m = e & 31;
        int cell = cell0 + m;
        int b = cell / NN, n = cell - b * NN;
        idxbuf[t * CPB + m] = (int)X[(((size_t)b * TT + t) * NN + n) * FF + 7];
    }
    if (tid < CPB) xbuf[tid] = xn[cell0 + tid];

    // ---- persistent B fragments: Whh^T, bf16 (24 VGPRs) ----
    bf16x8 Bf[3][2];
    #pragma unroll
    for (int gate = 0; gate < 3; ++gate) {
        #pragma unroll
        for (int ks = 0; ks < 2; ++ks) {
            const float* src = Whh + (size_t)(gate * HID + jcol) * HID + ks * 32 + quad * 8;
            float4 lo = *(const float4*)src;
            float4 hi = *(const float4*)(src + 4);
            bf16x8 f;
            f[0] = (short)f2bf(lo.x); f[1] = (short)f2bf(lo.y);
            f[2] = (short)f2bf(lo.z); f[3] = (short)f2bf(lo.w);
            f[4] = (short)f2bf(hi.x); f[5] = (short)f2bf(hi.y);
            f[6] = (short)f2bf(hi.z); f[7] = (short)f2bf(hi.w);
            Bf[gate][ks] = f;
        }
    }
    // ---- Wih embedding-part fragments (cols 1..32), bf16 (12 VGPRs) ----
    bf16x8 BX[3];
    #pragma unroll
    for (int gate = 0; gate < 3; ++gate) {
        const float* src = Wih + (size_t)(gate * HID + jcol) * INSZ + 1 + quad * 8;
        bf16x8 f;
        #pragma unroll
        for (int e = 0; e < 8; ++e) f[e] = (short)f2bf(src[e]);
        BX[gate] = f;
    }

    const float w0r = Wih[(size_t)jcol * INSZ];
    const float w0z = Wih[(size_t)(HID + jcol) * INSZ];
    const float w0n = Wih[(size_t)(2 * HID + jcol) * INSZ];
    // biases folded into MFMA C operands
    const float br  = bih[jcol] + bhh[jcol];
    const float bz  = bih[HID + jcol] + bhh[HID + jcol];
    const float bni = bih[2 * HID + jcol];
    const float bhn = bhh[2 * HID + jcol];
    const float bout0 = bout[0];

    // ---- out-dot role: wave g covers cells g*8..g*8+7, 8 lanes/cell ----
    const int cd_m   = g * 8 + (lane & 7);
    const int kslice = lane >> 3;          // 0..7, 8 k's each
    float wout_r[8];
    #pragma unroll
    for (int e2 = 0; e2 < 8; ++e2) wout_r[e2] = Wout[kslice * 8 + e2];
    const int cd_cell = cell0 + cd_m;
    const int cd_b = cd_cell / NN, cd_n = cd_cell - cd_b * NN;
    const size_t obase = (size_t)cd_b * FC * NN + cd_n;

    // ---- h0: fp32 regs + bf16 Abuf ----
    float hold[MT][4];
    #pragma unroll
    for (int mt = 0; mt < MT; ++mt) {
        #pragma unroll
        for (int rr = 0; rr < 4; ++rr) {
            int m = mt * 16 + rowb + rr;
            float h = hn0[((size_t)cell0 + m) * HID + jcol];
            hold[mt][rr] = h;
            Abuf[m * AST + jcol] = f2bf(h);
        }
    }
    __syncthreads();   // idxbuf / xbuf / Abuf ready

    // ---- stage Xt[0] (emb rows for t=0) ----
    {
        int r8 = tid >> 3, k4 = (tid & 7) * 4;
        int idx = idxbuf[r8];
        float4 e4 = *(const float4*)(emb + (size_t)idx * EMBD + k4);
        unsigned p0 = cvt_pk_bf16(e4.x, e4.y);
        unsigned p1 = cvt_pk_bf16(e4.z, e4.w);
        *(uint2*)&Xt[0][r8 * XST + k4] = make_uint2(p0, p1);
    }
    __syncthreads();

    for (int t = 0; t < FC; ++t) {
        // ---- stage next step's emb tile (latency hides under MFMAs) ----
        if (t + 1 < FC) {
            int r8 = tid >> 3, k4 = (tid & 7) * 4;
            int idx = idxbuf[(t + 1) * CPB + r8];
            float4 e4 = *(const float4*)(emb + (size_t)idx * EMBD + k4);
            unsigned p0 = cvt_pk_bf16(e4.x, e4.y);
            unsigned p1 = cvt_pk_bf16(e4.z, e4.w);
            *(uint2*)&Xt[(t + 1) & 1][r8 * XST + k4] = make_uint2(p0, p1);
        }
        const unsigned short* Xc = Xt[t & 1];

        // ---- phase A: G = [x_emb | H] · W^T on matrix pipe, biases in C ----
        f32x4 accr[MT], accz[MT], accni[MT], accng[MT];
        #pragma unroll
        for (int mt = 0; mt < MT; ++mt) {
            const bf16x8 a0 = *(const bf16x8*)&Abuf[(mt * 16 + l15) * AST + quad * 8];
            const bf16x8 a1 = *(const bf16x8*)&Abuf[(mt * 16 + l15) * AST + 32 + quad * 8];
            const bf16x8 x0 = *(const bf16x8*)&Xc[(mt * 16 + l15) * XST + quad * 8];
            f32x4 cr  = {br,  br,  br,  br };
            f32x4 cz  = {bz,  bz,  bz,  bz };
            f32x4 cni = {bni, bni, bni, bni};
            f32x4 cng = {bhn, bhn, bhn, bhn};
            accr[mt]  = __builtin_amdgcn_mfma_f32_16x16x32_bf16(x0, BX[0], cr, 0, 0, 0);
            accr[mt]  = __builtin_amdgcn_mfma_f32_16x16x32_bf16(a0, Bf[0][0], accr[mt], 0, 0, 0);
            accr[mt]  = __builtin_amdgcn_mfma_f32_16x16x32_bf16(a1, Bf[0][1], accr[mt], 0, 0, 0);
            accz[mt]  = __builtin_amdgcn_mfma_f32_16x16x32_bf16(x0, BX[1], cz, 0, 0, 0);
            accz[mt]  = __builtin_amdgcn_mfma_f32_16x16x32_bf16(a0, Bf[1][0], accz[mt], 0, 0, 0);
            accz[mt]  = __builtin_amdgcn_mfma_f32_16x16x32_bf16(a1, Bf[1][1], accz[mt], 0, 0, 0);
            accni[mt] = __builtin_amdgcn_mfma_f32_16x16x32_bf16(x0, BX[2], cni, 0, 0, 0);
            accng[mt] = __builtin_amdgcn_mfma_f32_16x16x32_bf16(a0, Bf[2][0], cng, 0, 0, 0);
            accng[mt] = __builtin_amdgcn_mfma_f32_16x16x32_bf16(a1, Bf[2][1], accng[mt], 0, 0, 0);
        }

        // ---- overlapped: out-dot for step t-1 (reads Abuf only) ----
        if (t > 0) {
            bf16x8 hv = *(const bf16x8*)&Abuf[cd_m * AST + kslice * 8];
            const unsigned* hv32 = (const unsigned*)&hv;
            float o = 0.f;
            #pragma unroll
            for (int q = 0; q < 4; ++q) {
                unsigned v = hv32[q];
                o = fmaf(wout_r[2 * q],     __builtin_bit_cast(float, v << 16),         o);
                o = fmaf(wout_r[2 * q + 1], __builtin_bit_cast(float, v & 0xFFFF0000u), o);
            }
            o += __shfl_xor(o, 8);
            o += __shfl_xor(o, 16);
            o += __shfl_xor(o, 32);
            if (lane < 8) {
                float oo = o + bout0;
                out[obase + (size_t)(t - 1) * NN] = oo;
                xbuf[cd_m] = oo;
            }
        }
        __syncthreads();   // xbuf ready; Abuf/Xt reads drained before writes

        // ---- phase B: gates + h update (no global gather, no bias adds) ----
        #pragma unroll
        for (int mt = 0; mt < MT; ++mt) {
            #pragma unroll
            for (int rp = 0; rp < 2; ++rp) {
                float h2[2];
                #pragma unroll
                for (int k = 0; k < 2; ++k) {
                    const int rr = rp * 2 + k;
                    const int m  = mt * 16 + rowb + rr;
                    float xp = xbuf[m];
                    float r  = fast_sigmoid(fmaf(w0r, xp, accr[mt][rr]));
                    float z  = fast_sigmoid(fmaf(w0z, xp, accz[mt][rr]));
                    float nv = fast_tanh(fmaf(r, accng[mt][rr],
                                              fmaf(w0n, xp, accni[mt][rr])));
                    float hnew = nv + z * (hold[mt][rr] - nv);
                    hold[mt][rr] = hnew;
                    h2[k] = hnew;
                }
                unsigned pk = cvt_pk_bf16(h2[0], h2[1]);
                const int m0 = mt * 16 + rowb + rp * 2;
                Abuf[m0 * AST + jcol]       = (unsigned short)pk;
                Abuf[(m0 + 1) * AST + jcol] = (unsigned short)(pk >> 16);
            }
        }
        __syncthreads();   // h_new complete for next A / out-dot
    }

    // ---- epilogue: out for final step ----
    {
        bf16x8 hv = *(const bf16x8*)&Abuf[cd_m * AST + kslice * 8];
        const unsigned* hv32 = (const unsigned*)&hv;
        float o = 0.f;
        #pragma unroll
        for (int q = 0; q < 4; ++q) {
            unsigned v = hv32[q];
            o = fmaf(wout_r[2 * q],     __builtin_bit_cast(float, v << 16),         o);
            o = fmaf(wout_r[2 * q + 1], __builtin_bit_cast(float, v & 0xFFFF0000u), o);
        }
        o += __shfl_xor(o, 8);
        o += __shfl_xor(o, 16);
        o += __shfl_xor(o, 32);
        if (lane < 8) out[obase + (size_t)(FC - 1) * NN] = o + bout0;
    }
}

extern "C" void kernel_launch(void* const* d_in, const int* in_sizes, int n_in,
                              void* d_out, int out_size, void* d_ws, size_t ws_size,
                              hipStream_t stream) {
    (void)in_sizes; (void)n_in; (void)out_size; (void)d_ws; (void)ws_size;
    const float* X    = (const float*)d_in[0];
    const float* hn   = (const float*)d_in[1];
    const float* xn   = (const float*)d_in[2];
    const float* emb  = (const float*)d_in[3];
    const float* Wih  = (const float*)d_in[4];
    const float* Whh  = (const float*)d_in[5];
    const float* bih  = (const float*)d_in[6];
    const float* bhh  = (const float*)d_in[7];
    const float* Wout = (const float*)d_in[8];
    const float* bout = (const float*)d_in[9];
    float* out = (float*)d_out;

    const int blocks = (BB * NN) / CPB;   // 2000
    gru_decoder<<<blocks, TPB, 0, stream>>>(X, hn, xn, emb, Wih, Whh,
                                            bih, bhh, Wout, bout, out);
}

// Round 2
// 265.130 us; speedup vs baseline: 2.0536x; 2.0536x over previous
//
#include <hip/hip_runtime.h>
#include <math.h>

// Problem constants
#define BB   64
#define FC   24
#define NN   1000
#define HID  64
#define EMBD 32
#define TT   48
#define FF   8
#define NEMB 1000
#define G3   192
#define INSZ 33

// Decoder tiling
#define CPB  32     // cells per block (M)
#define TPB  256    // 4 waves
#define MT   2      // m-tiles of 16
#define AST  72     // Abuf stride in bf16 elems (16B-aligned rows)
#define XST  32     // Xtile stride in bf16 elems (64B rows, 16B-aligned)

typedef __attribute__((ext_vector_type(8))) short bf16x8;
typedef __attribute__((ext_vector_type(4))) float f32x4;

static __device__ __forceinline__ unsigned short f2bf(float f) {
    unsigned u = __builtin_bit_cast(unsigned, f);
    u += 0x7FFFu + ((u >> 16) & 1u);      // RNE
    return (unsigned short)(u >> 16);
}
// packed RNE f32->bf16: lo = bf16(a), hi = bf16(b)
static __device__ __forceinline__ unsigned cvt_pk_bf16(float a, float b) {
    unsigned r;
    asm("v_cvt_pk_bf16_f32 %0, %1, %2" : "=v"(r) : "v"(a), "v"(b));
    return r;
}
static __device__ __forceinline__ float fast_sigmoid(float v) {
    float e = __builtin_amdgcn_exp2f(-1.4426950408889634f * v);
    return __builtin_amdgcn_rcpf(1.0f + e);
}
static __device__ __forceinline__ float fast_tanh(float v) {
    float vv = fminf(fmaxf(v, -15.0f), 15.0f);
    float e = __builtin_amdgcn_exp2f(2.8853900817779268f * vv);
    return 1.0f - 2.0f * __builtin_amdgcn_rcpf(e + 1.0f);
}

// Workgroup barrier that drains ONLY lgkmcnt (LDS), not vmcnt.
// Safe here: global ops in flight are register loads (private) and the
// `out` store (never read in-kernel). Avoids the vmcnt(0) drain that
// __syncthreads() emits, so the prefetched emb gather stays in flight.
static __device__ __forceinline__ void lds_barrier() {
    __builtin_amdgcn_sched_barrier(0);
    asm volatile("s_waitcnt lgkmcnt(0)" ::: "memory");
    __builtin_amdgcn_s_barrier();
    __builtin_amdgcn_sched_barrier(0);
}

__global__ __launch_bounds__(TPB) __attribute__((amdgpu_waves_per_eu(3)))
void gru_decoder(
    const float* __restrict__ X,    // [B][TT][N][F]
    const float* __restrict__ hn0,  // [B*N][HID]
    const float* __restrict__ xn,   // [B][N][1]
    const float* __restrict__ emb,  // [NEMB][EMBD]
    const float* __restrict__ Wih,  // [3*HID][INSZ]
    const float* __restrict__ Whh,  // [3*HID][HID]
    const float* __restrict__ bih,  // [3*HID]
    const float* __restrict__ bhh,  // [3*HID]
    const float* __restrict__ Wout, // [1][HID]
    const float* __restrict__ bout, // [1]
    float* __restrict__ out)        // [B][FC][N][1]
{
    __shared__ __align__(16) unsigned short Abuf[CPB * AST];     // 4608 B
    __shared__ __align__(16) unsigned short Xt[2][CPB * XST];    // 4096 B
    __shared__ int   idxbuf[FC * CPB];                           // 3072 B
    __shared__ float xbuf[CPB];

    const int tid  = threadIdx.x;
    const int lane = tid & 63;
    const int g    = tid >> 6;         // wave 0..3, owns gate-cols g*16..g*16+15
    const int quad = lane >> 4;
    const int l15  = lane & 15;
    const int jcol = g * 16 + l15;
    const int rowb = quad * 4;
    const int cell0 = blockIdx.x * CPB;

    // ---- stage idx for all FC steps ----
    for (int e = tid; e < FC * CPB; e += TPB) {
        int t = e >> 5, m = e & 31;
        int cell = cell0 + m;
        int b = cell / NN, n = cell - b * NN;
        idxbuf[t * CPB + m] = (int)X[(((size_t)b * TT + t) * NN + n) * FF + 7];
    }
    if (tid < CPB) xbuf[tid] = xn[cell0 + tid];

    // ---- persistent B fragments: Whh^T, bf16 (24 VGPRs) ----
    bf16x8 Bf[3][2];
    #pragma unroll
    for (int gate = 0; gate < 3; ++gate) {
        #pragma unroll
        for (int ks = 0; ks < 2; ++ks) {
            const float* src = Whh + (size_t)(gate * HID + jcol) * HID + ks * 32 + quad * 8;
            float4 lo = *(const float4*)src;
            float4 hi = *(const float4*)(src + 4);
            bf16x8 f;
            f[0] = (short)f2bf(lo.x); f[1] = (short)f2bf(lo.y);
            f[2] = (short)f2bf(lo.z); f[3] = (short)f2bf(lo.w);
            f[4] = (short)f2bf(hi.x); f[5] = (short)f2bf(hi.y);
            f[6] = (short)f2bf(hi.z); f[7] = (short)f2bf(hi.w);
            Bf[gate][ks] = f;
        }
    }
    // ---- Wih embedding-part fragments (cols 1..32), bf16 (12 VGPRs) ----
    bf16x8 BX[3];
    #pragma unroll
    for (int gate = 0; gate < 3; ++gate) {
        const float* src = Wih + (size_t)(gate * HID + jcol) * INSZ + 1 + quad * 8;
        bf16x8 f;
        #pragma unroll
        for (int e = 0; e < 8; ++e) f[e] = (short)f2bf(src[e]);
        BX[gate] = f;
    }

    const float w0r = Wih[(size_t)jcol * INSZ];
    const float w0z = Wih[(size_t)(HID + jcol) * INSZ];
    const float w0n = Wih[(size_t)(2 * HID + jcol) * INSZ];
    // biases folded into MFMA C operands (loop-invariant broadcast vectors)
    const float br  = bih[jcol] + bhh[jcol];
    const float bz  = bih[HID + jcol] + bhh[HID + jcol];
    const float bni = bih[2 * HID + jcol];
    const float bhn = bhh[2 * HID + jcol];
    const f32x4 cr  = {br,  br,  br,  br };
    const f32x4 cz  = {bz,  bz,  bz,  bz };
    const f32x4 cni = {bni, bni, bni, bni};
    const f32x4 cng = {bhn, bhn, bhn, bhn};
    const float bout0 = bout[0];

    // ---- out-dot role: wave g covers cells g*8..g*8+7, 8 lanes/cell ----
    const int cd_m   = g * 8 + (lane & 7);
    const int kslice = lane >> 3;          // 0..7, 8 k's each
    float wout_r[8];
    #pragma unroll
    for (int e2 = 0; e2 < 8; ++e2) wout_r[e2] = Wout[kslice * 8 + e2];
    const int cd_cell = cell0 + cd_m;
    const int cd_b = cd_cell / NN, cd_n = cd_cell - cd_b * NN;
    const size_t obase = (size_t)cd_b * FC * NN + cd_n;

    // ---- h0: fp32 regs + bf16 Abuf ----
    float hold[MT][4];
    #pragma unroll
    for (int mt = 0; mt < MT; ++mt) {
        #pragma unroll
        for (int rr = 0; rr < 4; ++rr) {
            int m = mt * 16 + rowb + rr;
            float h = hn0[((size_t)cell0 + m) * HID + jcol];
            hold[mt][rr] = h;
            Abuf[m * AST + jcol] = f2bf(h);
        }
    }
    __syncthreads();   // idxbuf / xbuf / Abuf ready

    // ---- stage Xt[0] (emb rows for t=0) ----
    const int r8 = tid >> 3, k4 = (tid & 7) * 4;
    {
        int idx = idxbuf[r8];
        float4 e4 = *(const float4*)(emb + (size_t)idx * EMBD + k4);
        unsigned p0 = cvt_pk_bf16(e4.x, e4.y);
        unsigned p1 = cvt_pk_bf16(e4.z, e4.w);
        *(uint2*)&Xt[0][r8 * XST + k4] = make_uint2(p0, p1);
    }
    __syncthreads();

    for (int t = 0; t < FC; ++t) {
        // ---- issue next-step emb gather EARLY; consumed after phase B ----
        const int tn = (t + 1 < FC) ? t + 1 : FC - 1;   // clamped: unconditional
        const int nidx = idxbuf[tn * CPB + r8];
        const float4 e4 = *(const float4*)(emb + (size_t)nidx * EMBD + k4);

        const unsigned short* Xc = Xt[t & 1];

        // ---- phase A: G = [x_emb | H] · W^T on matrix pipe, biases in C ----
        f32x4 accr[MT], accz[MT], accni[MT], accng[MT];
        #pragma unroll
        for (int mt = 0; mt < MT; ++mt) {
            const bf16x8 a0 = *(const bf16x8*)&Abuf[(mt * 16 + l15) * AST + quad * 8];
            const bf16x8 a1 = *(const bf16x8*)&Abuf[(mt * 16 + l15) * AST + 32 + quad * 8];
            const bf16x8 x0 = *(const bf16x8*)&Xc[(mt * 16 + l15) * XST + quad * 8];
            accr[mt]  = __builtin_amdgcn_mfma_f32_16x16x32_bf16(x0, BX[0], cr, 0, 0, 0);
            accr[mt]  = __builtin_amdgcn_mfma_f32_16x16x32_bf16(a0, Bf[0][0], accr[mt], 0, 0, 0);
            accr[mt]  = __builtin_amdgcn_mfma_f32_16x16x32_bf16(a1, Bf[0][1], accr[mt], 0, 0, 0);
            accz[mt]  = __builtin_amdgcn_mfma_f32_16x16x32_bf16(x0, BX[1], cz, 0, 0, 0);
            accz[mt]  = __builtin_amdgcn_mfma_f32_16x16x32_bf16(a0, Bf[1][0], accz[mt], 0, 0, 0);
            accz[mt]  = __builtin_amdgcn_mfma_f32_16x16x32_bf16(a1, Bf[1][1], accz[mt], 0, 0, 0);
            accni[mt] = __builtin_amdgcn_mfma_f32_16x16x32_bf16(x0, BX[2], cni, 0, 0, 0);
            accng[mt] = __builtin_amdgcn_mfma_f32_16x16x32_bf16(a0, Bf[2][0], cng, 0, 0, 0);
            accng[mt] = __builtin_amdgcn_mfma_f32_16x16x32_bf16(a1, Bf[2][1], accng[mt], 0, 0, 0);
        }

        // ---- overlapped: out-dot for step t-1 (reads Abuf only) ----
        if (t > 0) {
            bf16x8 hv = *(const bf16x8*)&Abuf[cd_m * AST + kslice * 8];
            const unsigned* hv32 = (const unsigned*)&hv;
            float o = 0.f;
            #pragma unroll
            for (int q = 0; q < 4; ++q) {
                unsigned v = hv32[q];
                o = fmaf(wout_r[2 * q],     __builtin_bit_cast(float, v << 16),         o);
                o = fmaf(wout_r[2 * q + 1], __builtin_bit_cast(float, v & 0xFFFF0000u), o);
            }
            o += __shfl_xor(o, 8);
            o += __shfl_xor(o, 16);
            o += __shfl_xor(o, 32);
            if (lane < 8) {
                float oo = o + bout0;
                out[obase + (size_t)(t - 1) * NN] = oo;
                xbuf[cd_m] = oo;
            }
        }
        lds_barrier();   // xbuf ready; Abuf/Xt reads drained before writes

        // ---- phase B: gates + h update ----
        #pragma unroll
        for (int mt = 0; mt < MT; ++mt) {
            #pragma unroll
            for (int rp = 0; rp < 2; ++rp) {
                float h2[2];
                #pragma unroll
                for (int k = 0; k < 2; ++k) {
                    const int rr = rp * 2 + k;
                    const int m  = mt * 16 + rowb + rr;
                    float xp = xbuf[m];
                    float r  = fast_sigmoid(fmaf(w0r, xp, accr[mt][rr]));
                    float z  = fast_sigmoid(fmaf(w0z, xp, accz[mt][rr]));
                    float nv = fast_tanh(fmaf(r, accng[mt][rr],
                                              fmaf(w0n, xp, accni[mt][rr])));
                    float hnew = nv + z * (hold[mt][rr] - nv);
                    hold[mt][rr] = hnew;
                    h2[k] = hnew;
                }
                unsigned pk = cvt_pk_bf16(h2[0], h2[1]);
                const int m0 = mt * 16 + rowb + rp * 2;
                Abuf[m0 * AST + jcol]       = (unsigned short)pk;
                Abuf[(m0 + 1) * AST + jcol] = (unsigned short)(pk >> 16);
            }
        }

        // ---- late half of the async stage: vmcnt wait lands HERE ----
        {
            unsigned p0 = cvt_pk_bf16(e4.x, e4.y);
            unsigned p1 = cvt_pk_bf16(e4.z, e4.w);
            *(uint2*)&Xt[(t + 1) & 1][r8 * XST + k4] = make_uint2(p0, p1);
        }
        lds_barrier();   // h_new + next X tile complete for next phase A
    }

    // ---- epilogue: out for final step ----
    {
        bf16x8 hv = *(const bf16x8*)&Abuf[cd_m * AST + kslice * 8];
        const unsigned* hv32 = (const unsigned*)&hv;
        float o = 0.f;
        #pragma unroll
        for (int q = 0; q < 4; ++q) {
            unsigned v = hv32[q];
            o = fmaf(wout_r[2 * q],     __builtin_bit_cast(float, v << 16),         o);
            o = fmaf(wout_r[2 * q + 1], __builtin_bit_cast(float, v & 0xFFFF0000u), o);
        }
        o += __shfl_xor(o, 8);
        o += __shfl_xor(o, 16);
        o += __shfl_xor(o, 32);
        if (lane < 8) out[obase + (size_t)(FC - 1) * NN] = o + bout0;
    }
}

extern "C" void kernel_launch(void* const* d_in, const int* in_sizes, int n_in,
                              void* d_out, int out_size, void* d_ws, size_t ws_size,
                              hipStream_t stream) {
    (void)in_sizes; (void)n_in; (void)out_size; (void)d_ws; (void)ws_size;
    const float* X    = (const float*)d_in[0];
    const float* hn   = (const float*)d_in[1];
    const float* xn   = (const float*)d_in[2];
    const float* emb  = (const float*)d_in[3];
    const float* Wih  = (const float*)d_in[4];
    const float* Whh  = (const float*)d_in[5];
    const float* bih  = (const float*)d_in[6];
    const float* bhh  = (const float*)d_in[7];
    const float* Wout = (const float*)d_in[8];
    const float* bout = (const float*)d_in[9];
    float* out = (float*)d_out;

    const int blocks = (BB * NN) / CPB;   // 2000
    gru_decoder<<<blocks, TPB, 0, stream>>>(X, hn, xn, emb, Wih, Whh,
                                            bih, bhh, Wout, bout, out);
}